// Round 2
// baseline (8077.683 us; speedup 1.0000x reference)
//
#include <hip/hip_runtime.h>
#include <cstdint>
#include <cstddef>

typedef short bf16x8 __attribute__((ext_vector_type(8)));
typedef float f32x4 __attribute__((ext_vector_type(4)));

#define DEVI static __device__ __forceinline__

DEVI unsigned short f2bf(float f) {
  union { float f; unsigned u; } v; v.f = f;
  unsigned r = (v.u + 0x7fffu + ((v.u >> 16) & 1u)) >> 16;
  return (unsigned short)r;
}
DEVI float bf2f(unsigned short s) {
  union { unsigned u; float f; } v; v.u = ((unsigned)s) << 16;
  return v.f;
}
DEVI float sigf(float x) { return 1.f / (1.f + __expf(-x)); }
DEVI float tanh_f(float x) {
  float xc = fminf(fmaxf(x, -15.f), 15.f);
  float e = __expf(2.f * xc);
  return 1.f - 2.f / (e + 1.f);
}

// d_out float offsets
#define DO_ET     0
#define DO_PRT    3200
#define DO_POPT   3968
#define DO_H      4480
#define DO_C      37248
#define DO_PENAL  70016
#define DO_A      70017

// ================= K1: pack weights (bf16, fragment-major), zero flags/penal ==============
__global__ __launch_bounds__(256) void k_pack(
    const float* __restrict__ Wih_f, const float* __restrict__ Wih_b,
    const float* __restrict__ Whh_f, const float* __restrict__ Whh_b,
    const float* __restrict__ S1,
    unsigned short* __restrict__ BihP, unsigned short* __restrict__ BhhP,
    unsigned short* __restrict__ S1P, int* __restrict__ flags, float* __restrict__ dout)
{
  int idx = blockIdx.x * 256 + threadIdx.x;
  if (idx < 655360) {
    // Bih: [d][kb=40][n=1024][j=8]; n = ht*128 + g*32 + u -> orig col g*256+ht*32+u
    int d = idx / 327680; int e = idx % 327680;
    int kb = e / 8192; int rem = e % 8192; int n = rem >> 3; int j = rem & 7;
    int k = kb * 8 + j;
    int col = ((n >> 5) & 3) * 256 + ((n >> 7) << 5) + (n & 31);
    const float* W = d ? Wih_b : Wih_f;
    float v = (k < 300) ? W[col * 300 + k] : 0.f;
    BihP[idx] = f2bf(v);
  } else if (idx < 1179648) {
    // Bhh: [d][ht=8][kb=32][c=128][j=8]; c = g*32+u -> row g*256+ht*32+u
    int e = idx - 655360;
    int d = e >> 18; int e2 = e & 262143;
    int ht = (e2 >> 15) & 7; int kb = (e2 >> 10) & 31; int c = (e2 >> 3) & 127; int j = e2 & 7;
    int k = kb * 8 + j;
    int row = ((c >> 5) << 8) + (ht << 5) + (c & 31);
    const float* W = d ? Whh_b : Whh_f;
    BhhP[e] = f2bf(W[row * 256 + k]);
  } else if (idx < 1212416) {
    // S1P: [kb=64][da=64][j=8] = S1[da][kb*8+j]
    int e = idx - 1179648;
    int j = e & 7; int da = (e >> 3) & 63; int kb = e >> 9;
    S1P[e] = f2bf(S1[da * 512 + kb * 8 + j]);
  } else if (idx < 1213440) {
    flags[idx - 1212416] = 0;
  } else if (idx == 1213440) {
    dout[DO_PENAL] = 0.f;
  }
}

// ================= K2: fused gather GEMM (chunked) ==============
__global__ __launch_bounds__(256, 2) void k_xgemm(
    const int* __restrict__ ids, const int* __restrict__ len, const float* __restrict__ emb,
    const unsigned short* __restrict__ BihP, unsigned short* __restrict__ G,
    int chunk, int Tc)
{
  __shared__ int toks[128];
  __shared__ unsigned short Al[4 * 128 * 8];
  int tid = threadIdx.x;
  int t0l = blockIdx.x * 128;          // local time base within chunk
  int t0g = chunk * Tc + t0l;          // global time base
  int b = blockIdx.y;
  int z = blockIdx.z; int d = z >> 3; int ht = z & 7;
  int lane = tid & 63, w = tid >> 6, l15 = lane & 15, quad = lane >> 4;
  int wm = w & 1, wn = w >> 1;

  if (tid < 128) {
    int t = t0g + tid;
    int s;
    if (d) { int lb = len[b]; s = lb - 1 - t; s = s < 0 ? 0 : (s > 1023 ? 1023 : s); }
    else   { s = t > 1023 ? 1023 : t; }
    toks[tid] = ids[b * 1024 + s];
  }
  __syncthreads();

  f32x4 acc[4][4];
  #pragma unroll
  for (int i = 0; i < 4; ++i)
    #pragma unroll
    for (int jj = 0; jj < 4; ++jj) acc[i][jj] = (f32x4){0.f, 0.f, 0.f, 0.f};

  int m = tid & 127, half = tid >> 7;
  const unsigned short* Bbase = BihP + (size_t)d * 327680;

  for (int kc = 0; kc < 10; ++kc) {
    int k0 = kc * 32;
    float vals[16];
    {
      const float* row = emb + (size_t)toks[m] * 300 + k0 + half * 16;
      if (kc < 9) {
        #pragma unroll
        for (int q = 0; q < 4; ++q) {
          float4 f4 = *reinterpret_cast<const float4*>(row + q * 4);
          vals[q * 4 + 0] = f4.x; vals[q * 4 + 1] = f4.y;
          vals[q * 4 + 2] = f4.z; vals[q * 4 + 3] = f4.w;
        }
      } else {
        #pragma unroll
        for (int ii = 0; ii < 16; ++ii) {
          int k = k0 + half * 16 + ii;
          vals[ii] = (k < 300) ? row[ii] : 0.f;
        }
      }
    }
    bf16x8 bfr[4];
    #pragma unroll
    for (int nt = 0; nt < 4; ++nt) {
      int n = (ht << 7) + wn * 64 + nt * 16 + l15;
      bfr[nt] = *reinterpret_cast<const bf16x8*>(Bbase + ((size_t)(kc * 4 + quad) * 1024 + n) * 8);
    }
    if (kc) __syncthreads();
    #pragma unroll
    for (int q = 0; q < 2; ++q) {
      bf16x8 v;
      #pragma unroll
      for (int j = 0; j < 8; ++j) v[j] = (short)f2bf(vals[q * 8 + j]);
      *reinterpret_cast<bf16x8*>(&Al[(((half * 2 + q) * 128) + m) * 8]) = v;
    }
    __syncthreads();
    bf16x8 afr[4];
    #pragma unroll
    for (int mt = 0; mt < 4; ++mt) {
      int mm = wm * 64 + mt * 16 + l15;
      afr[mt] = *reinterpret_cast<const bf16x8*>(&Al[((quad * 128) + mm) * 8]);
    }
    #pragma unroll
    for (int mt = 0; mt < 4; ++mt)
      #pragma unroll
      for (int nt = 0; nt < 4; ++nt)
        acc[mt][nt] = __builtin_amdgcn_mfma_f32_16x16x32_bf16(afr[mt], bfr[nt], acc[mt][nt], 0, 0, 0);
  }

  size_t bstr = (size_t)Tc * 128;
  size_t gbase = ((size_t)(d * 8 + ht) * 64 + b) * bstr;
  #pragma unroll
  for (int mt = 0; mt < 4; ++mt)
    #pragma unroll
    for (int nt = 0; nt < 4; ++nt)
      #pragma unroll
      for (int r = 0; r < 4; ++r) {
        int mm = wm * 64 + mt * 16 + quad * 4 + r;
        int tl = t0l + mm;
        if (tl < Tc) {
          int nn = wn * 64 + nt * 16 + l15;
          G[gbase + (size_t)tl * 128 + nn] = f2bf(acc[mt][nt][r]);
        }
      }
}

// ================= K3: persistent bidirectional LSTM recurrence (chunked) ==========
__global__ __launch_bounds__(256, 2) void k_rnn(
    const unsigned short* __restrict__ G, const unsigned short* __restrict__ BhhP,
    unsigned short* __restrict__ Hbuf, unsigned short* __restrict__ Hout, int* flags,
    const int* __restrict__ len, const float* __restrict__ h0, const float* __restrict__ c0,
    float* __restrict__ CSc, float* __restrict__ CSh, float* __restrict__ dout,
    int t_begin, int t_count, int Tc)
{
  int blk = blockIdx.x;
  int d = blk >> 5, bt = (blk >> 3) & 3, ht = blk & 7;
  int tid = threadIdx.x;
  int lane = tid & 63, w = tid >> 6, l15 = lane & 15, quad = lane >> 4;
  int b0 = bt * 16;

  __shared__ unsigned short h0p[4096];
  __shared__ float gatesL[4 * 16 * 32];
  __shared__ int lenS[16];

  for (int i = tid; i < 4096; i += 256) {
    int kb = i >> 7, mm = (i >> 3) & 15, j = i & 7;
    h0p[i] = f2bf(h0[d * 16384 + (b0 + mm) * 256 + kb * 8 + j]);
  }
  if (tid < 16) lenS[tid] = len[b0 + tid];

  const unsigned short* Bw = BhhP + (size_t)(d * 8 + ht) * 262144;
  bf16x8 bfr[8][2];
  #pragma unroll
  for (int kc = 0; kc < 8; ++kc)
    #pragma unroll
    for (int nt = 0; nt < 2; ++nt)
      bfr[kc][nt] = *reinterpret_cast<const bf16x8*>(
          Bw + ((size_t)(kc * 4 + quad) * 128 + w * 32 + nt * 16 + l15) * 8);

  __syncthreads();

  int b_l = tid >> 4, u2 = tid & 15;
  int len_b = lenS[b_l];
  int Tmax = lenS[0];  // lens sorted descending
  int cidx = d * 16384 + (b0 + b_l) * 256 + ht * 32 + 2 * u2;
  float cc0, cc1, hh0, hh1;
  if (t_begin == 0) {
    cc0 = c0[cidx]; cc1 = c0[cidx + 1];
    hh0 = h0[cidx]; hh1 = h0[cidx + 1];
  } else {
    cc0 = CSc[cidx]; cc1 = CSc[cidx + 1];
    hh0 = CSh[cidx]; hh1 = CSh[cidx + 1];
  }

  size_t bstr = (size_t)Tc * 128;
  const unsigned short* Gw = G + ((size_t)(d * 8 + ht) * 64 + b0) * bstr;
  unsigned short* HbufG = Hbuf + (size_t)((d * 4 + bt) * 2) * 4096;
  int* fl = flags + (d * 4 + bt) * 128;

  int t_end = Tmax < t_begin + t_count ? Tmax : t_begin + t_count;

  for (int t = t_begin; t < t_end; ++t) {
    int tl = t - t_begin;
    // prefetch G tile (independent of h) before the spin
    unsigned short gld[2][4];
    #pragma unroll
    for (int nt = 0; nt < 2; ++nt)
      #pragma unroll
      for (int r = 0; r < 4; ++r)
        gld[nt][r] = Gw[(size_t)(quad * 4 + r) * bstr + (size_t)tl * 128 + w * 32 + nt * 16 + l15];

    if (t > 0) {
      int polls = 0;
      while (true) {
        int v = 0x7fffffff;
        if (lane < 8)
          v = __hip_atomic_load(fl + lane * 16, __ATOMIC_RELAXED, __HIP_MEMORY_SCOPE_AGENT);
        if (__ballot(v >= t) == ~0ull) break;
        if (++polls > 20000) break;  // failsafe: wrong answer instead of hang
      }
      __builtin_amdgcn_fence(__ATOMIC_ACQUIRE, "agent");
    }

    bf16x8 afr[8];
    if (t == 0) {
      #pragma unroll
      for (int kc = 0; kc < 8; ++kc)
        afr[kc] = *reinterpret_cast<const bf16x8*>(&h0p[((kc * 4 + quad) * 16 + l15) * 8]);
    } else {
      const unsigned short* hb = HbufG + (size_t)(t & 1) * 4096;
      #pragma unroll
      for (int kc = 0; kc < 8; ++kc)
        afr[kc] = *reinterpret_cast<const bf16x8*>(hb + ((kc * 4 + quad) * 16 + l15) * 8);
    }

    f32x4 ac0 = {0.f, 0.f, 0.f, 0.f}, ac1 = {0.f, 0.f, 0.f, 0.f};
    #pragma unroll
    for (int kc = 0; kc < 8; ++kc) {
      ac0 = __builtin_amdgcn_mfma_f32_16x16x32_bf16(afr[kc], bfr[kc][0], ac0, 0, 0, 0);
      ac1 = __builtin_amdgcn_mfma_f32_16x16x32_bf16(afr[kc], bfr[kc][1], ac1, 0, 0, 0);
    }
    #pragma unroll
    for (int r = 0; r < 4; ++r) { ac0[r] += bf2f(gld[0][r]); ac1[r] += bf2f(gld[1][r]); }

    #pragma unroll
    for (int r = 0; r < 4; ++r) {
      gatesL[(w * 16 + quad * 4 + r) * 32 + l15] = ac0[r];
      gatesL[(w * 16 + quad * 4 + r) * 32 + 16 + l15] = ac1[r];
    }
    __syncthreads();

    float gi0 = gatesL[(0 * 16 + b_l) * 32 + 2 * u2], gi1 = gatesL[(0 * 16 + b_l) * 32 + 2 * u2 + 1];
    float gf0 = gatesL[(1 * 16 + b_l) * 32 + 2 * u2], gf1 = gatesL[(1 * 16 + b_l) * 32 + 2 * u2 + 1];
    float gg0 = gatesL[(2 * 16 + b_l) * 32 + 2 * u2], gg1 = gatesL[(2 * 16 + b_l) * 32 + 2 * u2 + 1];
    float go0 = gatesL[(3 * 16 + b_l) * 32 + 2 * u2], go1 = gatesL[(3 * 16 + b_l) * 32 + 2 * u2 + 1];

    if (t < len_b) {
      float cn0 = sigf(gf0) * cc0 + sigf(gi0) * tanh_f(gg0);
      float cn1 = sigf(gf1) * cc1 + sigf(gi1) * tanh_f(gg1);
      cc0 = cn0; cc1 = cn1;
      hh0 = sigf(go0) * tanh_f(cn0);
      hh1 = sigf(go1) * tanh_f(cn1);
    }

    int k = ht * 32 + 2 * u2;
    unsigned hp = (unsigned)f2bf(hh0) | ((unsigned)f2bf(hh1) << 16);
    *reinterpret_cast<unsigned*>(HbufG + (size_t)((t + 1) & 1) * 4096 +
                                 ((k >> 3) * 128 + b_l * 8 + (k & 7))) = hp;

    size_t hob = (size_t)(b0 + b_l) * 524288;
    if (d == 0) {
      *reinterpret_cast<unsigned*>(Hout + hob + (size_t)t * 512 + k) = hp;
    } else if (t < len_b) {
      *reinterpret_cast<unsigned*>(Hout + hob + (size_t)(len_b - 1 - t) * 512 + 256 + k) = hp;
    }
    if (t == len_b - 1) {
      dout[DO_H + cidx] = hh0; dout[DO_H + cidx + 1] = hh1;
      dout[DO_C + cidx] = cc0; dout[DO_C + cidx + 1] = cc1;
    }

    __builtin_amdgcn_fence(__ATOMIC_RELEASE, "agent");
    __syncthreads();
    if (tid == 0)
      __hip_atomic_store(fl + ht * 16, t + 1, __ATOMIC_RELAXED, __HIP_MEMORY_SCOPE_AGENT);
  }

  // persist state for next chunk
  CSc[cidx] = cc0; CSc[cidx + 1] = cc1;
  CSh[cidx] = hh0; CSh[cidx + 1] = hh1;
}

// ================= K4: scores = tanh(Hout @ S1^T) @ S2^T ==========
__global__ __launch_bounds__(256, 2) void k_scores(
    const unsigned short* __restrict__ Hout, const unsigned short* __restrict__ S1P,
    const float* __restrict__ S2, float* __restrict__ scores)
{
  __shared__ float U[128 * 65];
  __shared__ float S2l[16 * 65];
  int tid = threadIdx.x;
  int t0 = blockIdx.x * 128;
  int b = blockIdx.y;
  int lane = tid & 63, w = tid >> 6, l15 = lane & 15, quad = lane >> 4;

  f32x4 acc[2][4];
  #pragma unroll
  for (int i = 0; i < 2; ++i)
    #pragma unroll
    for (int j = 0; j < 4; ++j) acc[i][j] = (f32x4){0.f, 0.f, 0.f, 0.f};

  for (int kc = 0; kc < 16; ++kc) {
    bf16x8 afr[2];
    #pragma unroll
    for (int mt = 0; mt < 2; ++mt) {
      int row = t0 + w * 32 + mt * 16 + l15;
      afr[mt] = *reinterpret_cast<const bf16x8*>(
          Hout + (size_t)b * 524288 + (size_t)row * 512 + kc * 32 + quad * 8);
    }
    bf16x8 bfr[4];
    #pragma unroll
    for (int nt = 0; nt < 4; ++nt)
      bfr[nt] = *reinterpret_cast<const bf16x8*>(
          S1P + ((size_t)(kc * 4 + quad) * 64 + nt * 16 + l15) * 8);
    #pragma unroll
    for (int mt = 0; mt < 2; ++mt)
      #pragma unroll
      for (int nt = 0; nt < 4; ++nt)
        acc[mt][nt] = __builtin_amdgcn_mfma_f32_16x16x32_bf16(afr[mt], bfr[nt], acc[mt][nt], 0, 0, 0);
  }
  #pragma unroll
  for (int mt = 0; mt < 2; ++mt)
    #pragma unroll
    for (int nt = 0; nt < 4; ++nt)
      #pragma unroll
      for (int r = 0; r < 4; ++r)
        U[(w * 32 + mt * 16 + quad * 4 + r) * 65 + nt * 16 + l15] = acc[mt][nt][r];
  for (int i = tid; i < 1024; i += 256) S2l[(i >> 6) * 65 + (i & 63)] = S2[i];
  __syncthreads();
  for (int i = tid; i < 8192; i += 256) {
    int row = i >> 6, c = i & 63;
    U[row * 65 + c] = tanh_f(U[row * 65 + c]);
  }
  __syncthreads();
  for (int idx = tid; idx < 2048; idx += 256) {
    int row = idx >> 4, r = idx & 15;
    float s = 0.f;
    #pragma unroll 8
    for (int da = 0; da < 64; ++da) s += U[row * 65 + da] * S2l[r * 65 + da];
    scores[((size_t)b * 16 + r) * 1024 + t0 + row] = s;
  }
}

// ================= K5: masked softmax -> A (exact zeros past len) =========
__global__ __launch_bounds__(256) void k_softmax(
    const float* __restrict__ scores, const int* __restrict__ len, float* __restrict__ dout)
{
  __shared__ float red[256];
  int b = blockIdx.x, r = blockIdx.y;
  int tid = threadIdx.x;
  int lb = len[b];
  const float* src = scores + ((size_t)b * 16 + r) * 1024;
  float v[4]; float mx = -3.0e38f;
  #pragma unroll
  for (int i = 0; i < 4; ++i) {
    int t = tid + i * 256;
    v[i] = (t < lb) ? src[t] : -3.0e38f;
    mx = fmaxf(mx, v[i]);
  }
  red[tid] = mx; __syncthreads();
  for (int s = 128; s > 0; s >>= 1) { if (tid < s) red[tid] = fmaxf(red[tid], red[tid + s]); __syncthreads(); }
  float M = red[0]; __syncthreads();
  float se = 0.f;
  #pragma unroll
  for (int i = 0; i < 4; ++i) {
    int t = tid + i * 256;
    if (t < lb) { v[i] = __expf(v[i] - M); se += v[i]; }
  }
  red[tid] = se; __syncthreads();
  for (int s = 128; s > 0; s >>= 1) { if (tid < s) red[tid] += red[tid + s]; __syncthreads(); }
  float inv = 1.f / red[0];
  float* dst = dout + DO_A + ((size_t)b * 16 + r) * 1024;
  #pragma unroll
  for (int i = 0; i < 4; ++i) {
    int t = tid + i * 256;
    dst[t] = (t < lb) ? v[i] * inv : 0.f;
  }
}

// ================= K6: penal (2-pass, <=34KB LDS) =================
__global__ __launch_bounds__(256) void k_penal(float* __restrict__ dout)
{
  __shared__ float Al[16 * 513];
  __shared__ float red[256];
  int b = blockIdx.x, tid = threadIdx.x;
  const float* A = dout + DO_A + (size_t)b * 16384;
  int r = tid >> 4, q = tid & 15;
  float s = 0.f;
  for (int half = 0; half < 2; ++half) {
    __syncthreads();
    for (int i = tid; i < 8192; i += 256) {
      int rr = i >> 9, t = i & 511;
      Al[rr * 513 + t] = A[rr * 1024 + half * 512 + t];
    }
    __syncthreads();
    for (int t = 0; t < 512; ++t) s += Al[r * 513 + t] * Al[q * 513 + t];
  }
  float dv = s - ((r == q) ? 1.f : 0.f);
  red[tid] = dv * dv; __syncthreads();
  for (int st = 128; st > 0; st >>= 1) { if (tid < st) red[tid] += red[tid + st]; __syncthreads(); }
  if (tid == 0) atomicAdd(dout + DO_PENAL, red[0] * (1.f / 64.f));
}

// ================= K7: M = A @ Hout -> BM [64][8192] =================
__global__ __launch_bounds__(256) void k_attnM(
    const float* __restrict__ dout, const unsigned short* __restrict__ Hout,
    const int* __restrict__ len, float* __restrict__ Mws)
{
  int b = blockIdx.x, dc = blockIdx.y;
  int tid = threadIdx.x;
  int col = dc * 128 + (tid & 127);
  int rh = tid >> 7;
  int lb = len[b];
  const float* Ab = dout + DO_A + (size_t)b * 16384;
  const unsigned short* Hb = Hout + (size_t)b * 524288;
  float acc[8];
  #pragma unroll
  for (int i = 0; i < 8; ++i) acc[i] = 0.f;
  for (int t = 0; t < lb; ++t) {
    float h = bf2f(Hb[(size_t)t * 512 + col]);
    #pragma unroll
    for (int rr = 0; rr < 8; ++rr) acc[rr] += Ab[(rh * 8 + rr) * 1024 + t] * h;
  }
  #pragma unroll
  for (int rr = 0; rr < 8; ++rr) Mws[(size_t)b * 8192 + (rh * 8 + rr) * 512 + col] = acc[rr];
}

// ================= K8a: hidden = relu(BM @ W^T + b) =================
__global__ __launch_bounds__(256) void k_head1(
    const float* __restrict__ W, const float* __restrict__ bias,
    const float* __restrict__ Mws, float* __restrict__ hid)
{
  int tid = threadIdx.x;
  int n = blockIdx.x * 16 + (tid & 15);
  int bg = tid >> 4;
  const float* Wr = W + (size_t)n * 8192;
  float acc[4] = {0.f, 0.f, 0.f, 0.f};
  for (int k = 0; k < 8192; k += 4) {
    float4 wv = *reinterpret_cast<const float4*>(Wr + k);
    #pragma unroll
    for (int i = 0; i < 4; ++i) {
      float4 mv = *reinterpret_cast<const float4*>(Mws + (size_t)(bg * 4 + i) * 8192 + k);
      acc[i] += wv.x * mv.x + wv.y * mv.y + wv.z * mv.z + wv.w * mv.w;
    }
  }
  float bs = bias[n];
  #pragma unroll
  for (int i = 0; i < 4; ++i) hid[(size_t)(bg * 4 + i) * 512 + n] = fmaxf(acc[i] + bs, 0.f);
}

// ================= K8b: decoded = hidden @ Wd^T + bd =================
__global__ __launch_bounds__(256) void k_head2(
    const float* __restrict__ hid, const float* __restrict__ Wd, const float* __restrict__ bd,
    float* __restrict__ out, int No)
{
  int tid = threadIdx.x;
  for (int idx = tid; idx < 64 * No; idx += 256) {
    int b = idx / No, o = idx % No;
    const float* hv = hid + (size_t)b * 512;
    const float* wr = Wd + (size_t)o * 512;
    float acc = bd[o];
    for (int k = 0; k < 512; k += 4) {
      float4 h4 = *reinterpret_cast<const float4*>(hv + k);
      float4 w4 = *reinterpret_cast<const float4*>(wr + k);
      acc += h4.x * w4.x + h4.y * w4.y + h4.z * w4.z + h4.w * w4.w;
    }
    out[idx] = acc;
  }
}

extern "C" void kernel_launch(void* const* d_in, const int* in_sizes, int n_in,
                              void* d_out, int out_size, void* d_ws, size_t ws_size,
                              hipStream_t stream) {
  const int*   ids    = (const int*)d_in[0];
  const int*   len    = (const int*)d_in[1];
  const float* h0     = (const float*)d_in[2];
  const float* c0     = (const float*)d_in[3];
  const float* emb    = (const float*)d_in[4];
  const float* Wih_f  = (const float*)d_in[5];
  const float* Whh_f  = (const float*)d_in[6];
  const float* Wih_b  = (const float*)d_in[7];
  const float* Whh_b  = (const float*)d_in[8];
  const float* S1     = (const float*)d_in[9];
  const float* S2     = (const float*)d_in[10];
  const float* W_et   = (const float*)d_in[11];
  const float* b_et   = (const float*)d_in[12];
  const float* Wd_et  = (const float*)d_in[13];
  const float* bd_et  = (const float*)d_in[14];
  const float* W_prt  = (const float*)d_in[15];
  const float* b_prt  = (const float*)d_in[16];
  const float* Wd_prt = (const float*)d_in[17];
  const float* bd_prt = (const float*)d_in[18];
  const float* W_popt = (const float*)d_in[19];
  const float* b_popt = (const float*)d_in[20];
  const float* Wd_popt= (const float*)d_in[21];
  const float* bd_popt= (const float*)d_in[22];
  float* dout = (float*)d_out;
  char* ws = (char*)d_ws;

  // ---- runtime workspace layout (adaptive to ws_size) ----
  size_t off = 0;
  auto AL = [&](size_t bytes) { size_t r = off; off += (bytes + 255) & ~(size_t)255; return r; };
  size_t oHout = AL(67108864UL);   // [64][1024][512] bf16
  size_t oSc   = AL(4194304UL);    // [64][16][1024] f32
  size_t oM    = AL(2097152UL);    // [64][8192] f32
  size_t oHid  = AL(393216UL);     // [3][64][512] f32
  size_t oBih  = AL(1310720UL);    // packed W_ih
  size_t oBhh  = AL(1048576UL);    // packed W_hh
  size_t oS1P  = AL(65536UL);      // packed S1
  size_t oHbuf = AL(131072UL);     // h exchange, 8 groups x 2 slots x 4096 bf16
  size_t oCSc  = AL(131072UL);     // c state f32 [2][64][256]
  size_t oCSh  = AL(131072UL);     // h state f32
  size_t oFlag = AL(4096UL);       // 1024 ints
  size_t fixedB = off;

  int Tc = 32;
  if      (ws_size >= fixedB + 1024UL * 262144UL) Tc = 1024;
  else if (ws_size >= fixedB + 256UL * 262144UL)  Tc = 256;
  else if (ws_size >= fixedB + 128UL * 262144UL)  Tc = 128;
  else if (ws_size >= fixedB + 64UL * 262144UL)   Tc = 64;
  size_t oG = off;  // [2][8][64][Tc][128] bf16 = Tc*262144 bytes

  unsigned short* G    = (unsigned short*)(ws + oG);
  unsigned short* Hout = (unsigned short*)(ws + oHout);
  float* scores        = (float*)(ws + oSc);
  float* Mws           = (float*)(ws + oM);
  float* hid           = (float*)(ws + oHid);
  unsigned short* BihP = (unsigned short*)(ws + oBih);
  unsigned short* BhhP = (unsigned short*)(ws + oBhh);
  unsigned short* S1P  = (unsigned short*)(ws + oS1P);
  unsigned short* Hbuf = (unsigned short*)(ws + oHbuf);
  float* CSc           = (float*)(ws + oCSc);
  float* CSh           = (float*)(ws + oCSh);
  int* flags           = (int*)(ws + oFlag);

  hipLaunchKernelGGL(k_pack, dim3(4741), dim3(256), 0, stream,
                     Wih_f, Wih_b, Whh_f, Whh_b, S1, BihP, BhhP, S1P, flags, dout);

  int nchunk = 1024 / Tc;
  int gx = Tc >= 128 ? Tc / 128 : 1;
  for (int c = 0; c < nchunk; ++c) {
    hipLaunchKernelGGL(k_xgemm, dim3(gx, 64, 16), dim3(256), 0, stream,
                       ids, len, emb, BihP, G, c, Tc);
    hipLaunchKernelGGL(k_rnn, dim3(64), dim3(256), 0, stream,
                       G, BhhP, Hbuf, Hout, flags, len, h0, c0, CSc, CSh, dout,
                       c * Tc, Tc, Tc);
  }

  hipLaunchKernelGGL(k_scores, dim3(8, 64), dim3(256), 0, stream, Hout, S1P, S2, scores);
  hipLaunchKernelGGL(k_softmax, dim3(64, 16), dim3(256), 0, stream, scores, len, dout);
  hipLaunchKernelGGL(k_penal, dim3(64), dim3(256), 0, stream, dout);
  hipLaunchKernelGGL(k_attnM, dim3(64, 4), dim3(256), 0, stream, dout, Hout, len, Mws);
  hipLaunchKernelGGL(k_head1, dim3(32), dim3(256), 0, stream, W_et, b_et, Mws, hid);
  hipLaunchKernelGGL(k_head1, dim3(32), dim3(256), 0, stream, W_prt, b_prt, Mws, hid + 32768);
  hipLaunchKernelGGL(k_head1, dim3(32), dim3(256), 0, stream, W_popt, b_popt, Mws, hid + 65536);
  hipLaunchKernelGGL(k_head2, dim3(1), dim3(256), 0, stream, hid, Wd_et, bd_et, dout + DO_ET, 50);
  hipLaunchKernelGGL(k_head2, dim3(1), dim3(256), 0, stream, hid + 32768, Wd_prt, bd_prt, dout + DO_PRT, 12);
  hipLaunchKernelGGL(k_head2, dim3(1), dim3(256), 0, stream, hid + 65536, Wd_popt, bd_popt, dout + DO_POPT, 8);
}

// Round 4
// 4460.974 us; speedup vs baseline: 1.8107x; 1.8107x over previous
//
#include <hip/hip_runtime.h>
#include <cstdint>
#include <cstddef>

typedef short bf16x8 __attribute__((ext_vector_type(8)));
typedef float f32x4 __attribute__((ext_vector_type(4)));

#define DEVI static __device__ __forceinline__

DEVI unsigned short f2bf(float f) {
  union { float f; unsigned u; } v; v.f = f;
  unsigned r = (v.u + 0x7fffu + ((v.u >> 16) & 1u)) >> 16;
  return (unsigned short)r;
}
DEVI float bf2f(unsigned short s) {
  union { unsigned u; float f; } v; v.u = ((unsigned)s) << 16;
  return v.f;
}
DEVI float sigf(float x) { return 1.f / (1.f + __expf(-x)); }
DEVI float tanh_f(float x) {
  float xc = fminf(fmaxf(x, -15.f), 15.f);
  float e = __expf(2.f * xc);
  return 1.f - 2.f / (e + 1.f);
}
DEVI unsigned ldg_sc1(const unsigned* p) {
  return __hip_atomic_load(p, __ATOMIC_RELAXED, __HIP_MEMORY_SCOPE_AGENT);
}
DEVI unsigned long long ldg_sc1_64(const unsigned long long* p) {
  return __hip_atomic_load(p, __ATOMIC_RELAXED, __HIP_MEMORY_SCOPE_AGENT);
}
DEVI void stg_sc1(unsigned* p, unsigned v) {
  __hip_atomic_store(p, v, __ATOMIC_RELAXED, __HIP_MEMORY_SCOPE_AGENT);
}

// d_out float offsets
#define DO_ET     0
#define DO_PRT    3200
#define DO_POPT   3968
#define DO_H      4480
#define DO_C      37248
#define DO_PENAL  70016
#define DO_A      70017

// ================= K1: pack weights (bf16, fragment-major), zero flags/penal ==============
__global__ __launch_bounds__(256) void k_pack(
    const float* __restrict__ Wih_f, const float* __restrict__ Wih_b,
    const float* __restrict__ Whh_f, const float* __restrict__ Whh_b,
    const float* __restrict__ S1,
    unsigned short* __restrict__ BihP, unsigned short* __restrict__ BhhP,
    unsigned short* __restrict__ S1P, int* __restrict__ flags, float* __restrict__ dout)
{
  int idx = blockIdx.x * 256 + threadIdx.x;
  if (idx < 655360) {
    // Bih: [d][kb=40][n=1024][j=8]; n = ht*128 + g*32 + u -> orig col g*256+ht*32+u
    int d = idx / 327680; int e = idx % 327680;
    int kb = e / 8192; int rem = e % 8192; int n = rem >> 3; int j = rem & 7;
    int k = kb * 8 + j;
    int col = ((n >> 5) & 3) * 256 + ((n >> 7) << 5) + (n & 31);
    const float* W = d ? Wih_b : Wih_f;
    float v = (k < 300) ? W[col * 300 + k] : 0.f;
    BihP[idx] = f2bf(v);
  } else if (idx < 1179648) {
    // Bhh: [d][ht=8][kb=32][c=128][j=8]; per-(d,ht) block = 32768 shorts
    int e = idx - 655360;
    int d = e >> 18; int e2 = e & 262143;
    int ht = (e2 >> 15) & 7; int kb = (e2 >> 10) & 31; int c = (e2 >> 3) & 127; int j = e2 & 7;
    int k = kb * 8 + j;
    int row = ((c >> 5) << 8) + (ht << 5) + (c & 31);
    const float* W = d ? Whh_b : Whh_f;
    BhhP[e] = f2bf(W[row * 256 + k]);
  } else if (idx < 1212416) {
    // S1P: [kb=64][da=64][j=8]
    int e = idx - 1179648;
    int j = e & 7; int da = (e >> 3) & 63; int kb = e >> 9;
    S1P[e] = f2bf(S1[da * 512 + kb * 8 + j]);
  } else if (idx < 1213440) {
    flags[idx - 1212416] = 0;
  } else if (idx == 1213440) {
    dout[DO_PENAL] = 0.f;
  }
}

// ================= K2: gather GEMM, 32(t) x 512(n) per WG; wave w <-> ht block ==========
__global__ __launch_bounds__(256, 2) void k_xgemm(
    const int* __restrict__ ids, const int* __restrict__ len, const float* __restrict__ emb,
    const unsigned short* __restrict__ BihP, unsigned short* __restrict__ G,
    int chunk, int Tc)
{
  __shared__ int toks[32];
  __shared__ unsigned short Ah[1024];  // [kb=4][m=32][j=8]
  int tid = threadIdx.x;
  int t0l = blockIdx.x * 32;
  int t0g = chunk * Tc + t0l;
  int b = blockIdx.y;
  int z = blockIdx.z; int d = z >> 1; int zh = z & 1;
  int lane = tid & 63, w = tid >> 6, l15 = lane & 15, quad = lane >> 4;

  if (tid < 32) {
    int t = t0g + tid;
    int s;
    if (d) { int lb = len[b]; s = lb - 1 - t; s = s < 0 ? 0 : (s > 1023 ? 1023 : s); }
    else   { s = t > 1023 ? 1023 : t; }
    toks[tid] = ids[b * 1024 + s];
  }
  __syncthreads();

  f32x4 acc[2][8];
  #pragma unroll
  for (int i = 0; i < 2; ++i)
    #pragma unroll
    for (int j = 0; j < 8; ++j) acc[i][j] = (f32x4){0.f, 0.f, 0.f, 0.f};

  int m = tid & 31, kseg = tid >> 5;  // 8 segs x 4 floats = 32 K per iter
  const unsigned short* Bbase = BihP + (size_t)d * 327680;
  int nbase = zh * 512 + w * 128;     // permuted-n base; wave w owns ht = zh*4 + w

  for (int kc = 0; kc < 10; ++kc) {
    float v0 = 0.f, v1 = 0.f, v2 = 0.f, v3 = 0.f;
    if (kc < 9 || kseg < 3) {
      const float* row = emb + (size_t)toks[m] * 300 + kc * 32 + kseg * 4;
      float4 f4 = *reinterpret_cast<const float4*>(row);
      v0 = f4.x; v1 = f4.y; v2 = f4.z; v3 = f4.w;
    }
    bf16x8 bh[8];
    #pragma unroll
    for (int nt = 0; nt < 8; ++nt)
      bh[nt] = *reinterpret_cast<const bf16x8*>(
          Bbase + ((size_t)(kc * 4 + quad) * 1024 + nbase + nt * 16 + l15) * 8);
    if (kc) __syncthreads();
    {
      unsigned short h0s = f2bf(v0), h1s = f2bf(v1), h2s = f2bf(v2), h3s = f2bf(v3);
      int so = (((kseg >> 1) * 32 + m) * 8 + (kseg & 1) * 4) >> 1;  // dword idx
      ((unsigned*)Ah)[so]     = (unsigned)h0s | ((unsigned)h1s << 16);
      ((unsigned*)Ah)[so + 1] = (unsigned)h2s | ((unsigned)h3s << 16);
    }
    __syncthreads();
    bf16x8 ahf[2];
    #pragma unroll
    for (int mt = 0; mt < 2; ++mt)
      ahf[mt] = *reinterpret_cast<const bf16x8*>(&Ah[((quad * 32) + mt * 16 + l15) * 8]);
    #pragma unroll
    for (int mt = 0; mt < 2; ++mt)
      #pragma unroll
      for (int nt = 0; nt < 8; ++nt)
        acc[mt][nt] = __builtin_amdgcn_mfma_f32_16x16x32_bf16(ahf[mt], bh[nt], acc[mt][nt], 0, 0, 0);
  }

  size_t bstr = (size_t)Tc * 128;
  size_t gb = ((size_t)(d * 8 + zh * 4 + w) * 64 + b) * bstr;
  #pragma unroll
  for (int mt = 0; mt < 2; ++mt)
    #pragma unroll
    for (int nt = 0; nt < 8; ++nt)
      #pragma unroll
      for (int r = 0; r < 4; ++r) {
        int tl = t0l + mt * 16 + quad * 4 + r;
        G[gb + (size_t)tl * 128 + nt * 16 + l15] = f2bf(acc[mt][nt][r]);
      }
}

// ================= K3: persistent BiLSTM recurrence, fence-free IC handshake ==========
// 64 WGs: blk&7 = group (d,bt)  [XCD-affinity: members of a group share blk%8],
//         blk>>3 = ht. W_hh slice register-resident (FIXED stride 32768!).
__global__ __launch_bounds__(256, 2) void k_rnn(
    const unsigned short* __restrict__ G, const unsigned short* __restrict__ BhhP,
    unsigned short* __restrict__ Hbuf, unsigned short* __restrict__ Hout, int* flags,
    const int* __restrict__ len, const float* __restrict__ h0, const float* __restrict__ c0,
    float* __restrict__ CSc, float* __restrict__ CSh, float* __restrict__ dout,
    int t_begin, int t_count, int Tc)
{
  int blk = blockIdx.x;
  int ht = blk >> 3; int g = blk & 7; int d = g >> 2; int bt = g & 3;
  int tid = threadIdx.x;
  int lane = tid & 63, w = tid >> 6, l15 = lane & 15, quad = lane >> 4;
  int b0 = bt * 16;

  __shared__ unsigned short h0p[4096];   // [kb=32][m=16][j=8]
  __shared__ float gatesL[4 * 16 * 32];
  __shared__ int lenS[16];

  for (int i = tid; i < 4096; i += 256) {
    int kb = i >> 7, mm = (i >> 3) & 15, j = i & 7;
    h0p[i] = f2bf(h0[d * 16384 + (b0 + mm) * 256 + kb * 8 + j]);
  }
  if (tid < 16) lenS[tid] = len[b0 + tid];

  // register-resident W_hh slice; per-(d,ht) block = 32768 shorts (BUGFIX: was *262144)
  const unsigned short* Bw = BhhP + (size_t)(d * 8 + ht) * 32768;
  bf16x8 bfr[8][2];
  #pragma unroll
  for (int kc = 0; kc < 8; ++kc)
    #pragma unroll
    for (int nt = 0; nt < 2; ++nt)
      bfr[kc][nt] = *reinterpret_cast<const bf16x8*>(
          Bw + ((size_t)(kc * 4 + quad) * 128 + w * 32 + nt * 16 + l15) * 8);

  __syncthreads();

  int b_l = tid >> 4, u2 = tid & 15;
  int len_b = lenS[b_l];
  int Tmax = lenS[0];  // lens sorted descending
  int cidx = d * 16384 + (b0 + b_l) * 256 + ht * 32 + 2 * u2;
  float cc0, cc1, hh0, hh1;
  if (t_begin == 0) {
    cc0 = c0[cidx]; cc1 = c0[cidx + 1];
    hh0 = h0[cidx]; hh1 = h0[cidx + 1];
  } else {
    cc0 = CSc[cidx]; cc1 = CSc[cidx + 1];
    hh0 = CSh[cidx]; hh1 = CSh[cidx + 1];
  }

  size_t bstr = (size_t)Tc * 128;
  const unsigned short* Gw = G + ((size_t)(d * 8 + ht) * 64 + b0) * bstr;
  unsigned short* HbufG = Hbuf + (size_t)g * 8192;  // 2 slots x 4096 shorts
  int* fl = flags + g * 128;

  int t_end = Tmax < t_begin + t_count ? Tmax : t_begin + t_count;

  for (int t = t_begin; t < t_end; ++t) {
    int tl = t - t_begin;
    // prefetch G tile (independent of h) before the spin
    unsigned short gld[2][4];
    #pragma unroll
    for (int nt = 0; nt < 2; ++nt)
      #pragma unroll
      for (int r = 0; r < 4; ++r)
        gld[nt][r] = Gw[(size_t)(quad * 4 + r) * bstr + (size_t)tl * 128 + w * 32 + nt * 16 + l15];

    bf16x8 ah[8];
    if (t == 0) {
      #pragma unroll
      for (int kc = 0; kc < 8; ++kc)
        ah[kc] = *reinterpret_cast<const bf16x8*>(&h0p[((kc * 4 + quad) * 16 + l15) * 8]);
    } else {
      int polls = 0;
      while (true) {
        int v = 0x7fffffff;
        if (lane < 8)
          v = __hip_atomic_load(fl + lane * 16, __ATOMIC_RELAXED, __HIP_MEMORY_SCOPE_AGENT);
        if (__ballot(v >= t) == ~0ull) break;
        if (++polls > 100000) break;  // failsafe (never fires when protocol healthy)
      }
      asm volatile("" ::: "memory");
      const unsigned long long* slotU =
          (const unsigned long long*)(HbufG + (size_t)(t & 1) * 4096);
      #pragma unroll
      for (int kc = 0; kc < 8; ++kc) {
        int qo = (((kc * 4 + quad) * 16 + l15) * 4) >> 1;  // u64 index
        union { unsigned long long q[2]; bf16x8 v; } tu;
        tu.q[0] = ldg_sc1_64(slotU + qo);
        tu.q[1] = ldg_sc1_64(slotU + qo + 1);
        ah[kc] = tu.v;
      }
    }

    f32x4 ac0 = {0.f, 0.f, 0.f, 0.f}, ac1 = {0.f, 0.f, 0.f, 0.f};
    #pragma unroll
    for (int kc = 0; kc < 8; ++kc) {
      ac0 = __builtin_amdgcn_mfma_f32_16x16x32_bf16(ah[kc], bfr[kc][0], ac0, 0, 0, 0);
      ac1 = __builtin_amdgcn_mfma_f32_16x16x32_bf16(ah[kc], bfr[kc][1], ac1, 0, 0, 0);
    }
    #pragma unroll
    for (int r = 0; r < 4; ++r) { ac0[r] += bf2f(gld[0][r]); ac1[r] += bf2f(gld[1][r]); }

    #pragma unroll
    for (int r = 0; r < 4; ++r) {
      gatesL[(w * 16 + quad * 4 + r) * 32 + l15] = ac0[r];
      gatesL[(w * 16 + quad * 4 + r) * 32 + 16 + l15] = ac1[r];
    }
    __syncthreads();

    float gi0 = gatesL[(0 * 16 + b_l) * 32 + 2 * u2], gi1 = gatesL[(0 * 16 + b_l) * 32 + 2 * u2 + 1];
    float gf0 = gatesL[(1 * 16 + b_l) * 32 + 2 * u2], gf1 = gatesL[(1 * 16 + b_l) * 32 + 2 * u2 + 1];
    float gg0 = gatesL[(2 * 16 + b_l) * 32 + 2 * u2], gg1 = gatesL[(2 * 16 + b_l) * 32 + 2 * u2 + 1];
    float go0 = gatesL[(3 * 16 + b_l) * 32 + 2 * u2], go1 = gatesL[(3 * 16 + b_l) * 32 + 2 * u2 + 1];

    if (t < len_b) {
      float cn0 = sigf(gf0) * cc0 + sigf(gi0) * tanh_f(gg0);
      float cn1 = sigf(gf1) * cc1 + sigf(gi1) * tanh_f(gg1);
      cc0 = cn0; cc1 = cn1;
      hh0 = sigf(go0) * tanh_f(cn0);
      hh1 = sigf(go1) * tanh_f(cn1);
    }

    int k = ht * 32 + 2 * u2;
    unsigned hp = (unsigned)f2bf(hh0) | ((unsigned)f2bf(hh1) << 16);
    unsigned soff = ((unsigned)(k >> 3) * 128 + b_l * 8 + (k & 7)) >> 1;
    stg_sc1((unsigned*)(HbufG + (size_t)((t + 1) & 1) * 4096) + soff, hp);

    __syncthreads();  // drains vmcnt -> sc1 stores complete at coherence point
    if (tid == 0)
      __hip_atomic_store(fl + ht * 16, t + 1, __ATOMIC_RELAXED, __HIP_MEMORY_SCOPE_AGENT);

    // epilogue after flag post (not on the inter-WG critical path)
    size_t hob = (size_t)(b0 + b_l) * 524288;
    if (d == 0) {
      *reinterpret_cast<unsigned*>(Hout + hob + (size_t)t * 512 + k) = hp;
    } else if (t < len_b) {
      *reinterpret_cast<unsigned*>(Hout + hob + (size_t)(len_b - 1 - t) * 512 + 256 + k) = hp;
    }
    if (t == len_b - 1) {
      dout[DO_H + cidx] = hh0; dout[DO_H + cidx + 1] = hh1;
      dout[DO_C + cidx] = cc0; dout[DO_C + cidx + 1] = cc1;
    }
  }

  CSc[cidx] = cc0; CSc[cidx + 1] = cc1;
  CSh[cidx] = hh0; CSh[cidx + 1] = hh1;
}

// ================= K4: scores = tanh(Hout @ S1^T) @ S2^T ==========
__global__ __launch_bounds__(256, 2) void k_scores(
    const unsigned short* __restrict__ Hout, const unsigned short* __restrict__ S1P,
    const float* __restrict__ S2, float* __restrict__ scores)
{
  __shared__ float U[128 * 65];
  __shared__ float S2l[16 * 65];
  int tid = threadIdx.x;
  int t0 = blockIdx.x * 128;
  int b = blockIdx.y;
  int lane = tid & 63, w = tid >> 6, l15 = lane & 15, quad = lane >> 4;

  f32x4 acc[2][4];
  #pragma unroll
  for (int i = 0; i < 2; ++i)
    #pragma unroll
    for (int j = 0; j < 4; ++j) acc[i][j] = (f32x4){0.f, 0.f, 0.f, 0.f};

  for (int kc = 0; kc < 16; ++kc) {
    bf16x8 afr[2];
    #pragma unroll
    for (int mt = 0; mt < 2; ++mt) {
      int row = t0 + w * 32 + mt * 16 + l15;
      afr[mt] = *reinterpret_cast<const bf16x8*>(
          Hout + (size_t)b * 524288 + (size_t)row * 512 + kc * 32 + quad * 8);
    }
    bf16x8 bfr[4];
    #pragma unroll
    for (int nt = 0; nt < 4; ++nt)
      bfr[nt] = *reinterpret_cast<const bf16x8*>(
          S1P + ((size_t)(kc * 4 + quad) * 64 + nt * 16 + l15) * 8);
    #pragma unroll
    for (int mt = 0; mt < 2; ++mt)
      #pragma unroll
      for (int nt = 0; nt < 4; ++nt)
        acc[mt][nt] = __builtin_amdgcn_mfma_f32_16x16x32_bf16(afr[mt], bfr[nt], acc[mt][nt], 0, 0, 0);
  }
  #pragma unroll
  for (int mt = 0; mt < 2; ++mt)
    #pragma unroll
    for (int nt = 0; nt < 4; ++nt)
      #pragma unroll
      for (int r = 0; r < 4; ++r)
        U[(w * 32 + mt * 16 + quad * 4 + r) * 65 + nt * 16 + l15] = acc[mt][nt][r];
  for (int i = tid; i < 1024; i += 256) S2l[(i >> 6) * 65 + (i & 63)] = S2[i];
  __syncthreads();
  for (int i = tid; i < 8192; i += 256) {
    int row = i >> 6, c = i & 63;
    U[row * 65 + c] = tanh_f(U[row * 65 + c]);
  }
  __syncthreads();
  for (int idx = tid; idx < 2048; idx += 256) {
    int row = idx >> 4, r = idx & 15;
    float s = 0.f;
    #pragma unroll 8
    for (int da = 0; da < 64; ++da) s += U[row * 65 + da] * S2l[r * 65 + da];
    scores[((size_t)b * 16 + r) * 1024 + t0 + row] = s;
  }
}

// ================= K5: masked softmax -> A (exact zeros past len) =========
__global__ __launch_bounds__(256) void k_softmax(
    const float* __restrict__ scores, const int* __restrict__ len, float* __restrict__ dout)
{
  __shared__ float red[256];
  int b = blockIdx.x, r = blockIdx.y;
  int tid = threadIdx.x;
  int lb = len[b];
  const float* src = scores + ((size_t)b * 16 + r) * 1024;
  float v[4]; float mx = -3.0e38f;
  #pragma unroll
  for (int i = 0; i < 4; ++i) {
    int t = tid + i * 256;
    v[i] = (t < lb) ? src[t] : -3.0e38f;
    mx = fmaxf(mx, v[i]);
  }
  red[tid] = mx; __syncthreads();
  for (int s = 128; s > 0; s >>= 1) { if (tid < s) red[tid] = fmaxf(red[tid], red[tid + s]); __syncthreads(); }
  float M = red[0]; __syncthreads();
  float se = 0.f;
  #pragma unroll
  for (int i = 0; i < 4; ++i) {
    int t = tid + i * 256;
    if (t < lb) { v[i] = __expf(v[i] - M); se += v[i]; }
  }
  red[tid] = se; __syncthreads();
  for (int s = 128; s > 0; s >>= 1) { if (tid < s) red[tid] += red[tid + s]; __syncthreads(); }
  float inv = 1.f / red[0];
  float* dst = dout + DO_A + ((size_t)b * 16 + r) * 1024;
  #pragma unroll
  for (int i = 0; i < 4; ++i) {
    int t = tid + i * 256;
    dst[t] = (t < lb) ? v[i] * inv : 0.f;
  }
}

// ================= K6: penal (2-pass, <=34KB LDS) =================
__global__ __launch_bounds__(256) void k_penal(float* __restrict__ dout)
{
  __shared__ float Al[16 * 513];
  __shared__ float red[256];
  int b = blockIdx.x, tid = threadIdx.x;
  const float* A = dout + DO_A + (size_t)b * 16384;
  int r = tid >> 4, q = tid & 15;
  float s = 0.f;
  for (int half = 0; half < 2; ++half) {
    __syncthreads();
    for (int i = tid; i < 8192; i += 256) {
      int rr = i >> 9, t = i & 511;
      Al[rr * 513 + t] = A[rr * 1024 + half * 512 + t];
    }
    __syncthreads();
    for (int t = 0; t < 512; ++t) s += Al[r * 513 + t] * Al[q * 513 + t];
  }
  float dv = s - ((r == q) ? 1.f : 0.f);
  red[tid] = dv * dv; __syncthreads();
  for (int st = 128; st > 0; st >>= 1) { if (tid < st) red[tid] += red[tid + st]; __syncthreads(); }
  if (tid == 0) atomicAdd(dout + DO_PENAL, red[0] * (1.f / 64.f));
}

// ================= K7: M = A @ Hout -> BM [64][8192] =================
__global__ __launch_bounds__(256) void k_attnM(
    const float* __restrict__ dout, const unsigned short* __restrict__ Hout,
    const int* __restrict__ len, float* __restrict__ Mws)
{
  int b = blockIdx.x, dc = blockIdx.y;
  int tid = threadIdx.x;
  int col = dc * 128 + (tid & 127);
  int rh = tid >> 7;
  int lb = len[b];
  const float* Ab = dout + DO_A + (size_t)b * 16384;
  const unsigned short* Hb = Hout + (size_t)b * 524288;
  float acc[8];
  #pragma unroll
  for (int i = 0; i < 8; ++i) acc[i] = 0.f;
  for (int t = 0; t < lb; ++t) {
    float h = bf2f(Hb[(size_t)t * 512 + col]);
    #pragma unroll
    for (int rr = 0; rr < 8; ++rr) acc[rr] += Ab[(rh * 8 + rr) * 1024 + t] * h;
  }
  #pragma unroll
  for (int rr = 0; rr < 8; ++rr) Mws[(size_t)b * 8192 + (rh * 8 + rr) * 512 + col] = acc[rr];
}

// ================= K8a: hidden = relu(BM @ W^T + b) =================
__global__ __launch_bounds__(256) void k_head1(
    const float* __restrict__ W, const float* __restrict__ bias,
    const float* __restrict__ Mws, float* __restrict__ hid)
{
  int tid = threadIdx.x;
  int n = blockIdx.x * 16 + (tid & 15);
  int bg = tid >> 4;
  const float* Wr = W + (size_t)n * 8192;
  float acc[4] = {0.f, 0.f, 0.f, 0.f};
  for (int k = 0; k < 8192; k += 4) {
    float4 wv = *reinterpret_cast<const float4*>(Wr + k);
    #pragma unroll
    for (int i = 0; i < 4; ++i) {
      float4 mv = *reinterpret_cast<const float4*>(Mws + (size_t)(bg * 4 + i) * 8192 + k);
      acc[i] += wv.x * mv.x + wv.y * mv.y + wv.z * mv.z + wv.w * mv.w;
    }
  }
  float bs = bias[n];
  #pragma unroll
  for (int i = 0; i < 4; ++i) hid[(size_t)(bg * 4 + i) * 512 + n] = fmaxf(acc[i] + bs, 0.f);
}

// ================= K8b: decoded = hidden @ Wd^T + bd =================
__global__ __launch_bounds__(256) void k_head2(
    const float* __restrict__ hid, const float* __restrict__ Wd, const float* __restrict__ bd,
    float* __restrict__ out, int No)
{
  int tid = threadIdx.x;
  for (int idx = tid; idx < 64 * No; idx += 256) {
    int b = idx / No, o = idx % No;
    const float* hv = hid + (size_t)b * 512;
    const float* wr = Wd + (size_t)o * 512;
    float acc = bd[o];
    for (int k = 0; k < 512; k += 4) {
      float4 h4 = *reinterpret_cast<const float4*>(hv + k);
      float4 w4 = *reinterpret_cast<const float4*>(wr + k);
      acc += h4.x * w4.x + h4.y * w4.y + h4.z * w4.z + h4.w * w4.w;
    }
    out[idx] = acc;
  }
}

extern "C" void kernel_launch(void* const* d_in, const int* in_sizes, int n_in,
                              void* d_out, int out_size, void* d_ws, size_t ws_size,
                              hipStream_t stream) {
  const int*   ids    = (const int*)d_in[0];
  const int*   len    = (const int*)d_in[1];
  const float* h0     = (const float*)d_in[2];
  const float* c0     = (const float*)d_in[3];
  const float* emb    = (const float*)d_in[4];
  const float* Wih_f  = (const float*)d_in[5];
  const float* Whh_f  = (const float*)d_in[6];
  const float* Wih_b  = (const float*)d_in[7];
  const float* Whh_b  = (const float*)d_in[8];
  const float* S1     = (const float*)d_in[9];
  const float* S2     = (const float*)d_in[10];
  const float* W_et   = (const float*)d_in[11];
  const float* b_et   = (const float*)d_in[12];
  const float* Wd_et  = (const float*)d_in[13];
  const float* bd_et  = (const float*)d_in[14];
  const float* W_prt  = (const float*)d_in[15];
  const float* b_prt  = (const float*)d_in[16];
  const float* Wd_prt = (const float*)d_in[17];
  const float* bd_prt = (const float*)d_in[18];
  const float* W_popt = (const float*)d_in[19];
  const float* b_popt = (const float*)d_in[20];
  const float* Wd_popt= (const float*)d_in[21];
  const float* bd_popt= (const float*)d_in[22];
  float* dout = (float*)d_out;
  char* ws = (char*)d_ws;

  // ---- runtime workspace layout (adaptive to ws_size) ----
  size_t off = 0;
  auto AL = [&](size_t bytes) { size_t r = off; off += (bytes + 255) & ~(size_t)255; return r; };
  size_t oHout = AL(67108864UL);   // [64][1024][512] bf16
  size_t oBih  = AL(1310720UL);    // packed W_ih
  size_t oBhh  = AL(1048576UL);    // packed W_hh
  size_t oS1P  = AL(65536UL);      // packed S1
  size_t oHbuf = AL(131072UL);     // 8 groups x 2 slots x 4096 bf16
  size_t oCSc  = AL(131072UL);
  size_t oCSh  = AL(131072UL);
  size_t oFlag = AL(4096UL);
  size_t fixedB = off;

  int Tc = 32;
  if      (ws_size >= fixedB + 1024UL * 262144UL + 7000000UL) Tc = 1024;
  else if (ws_size >= fixedB + 256UL * 262144UL)  Tc = 256;
  else if (ws_size >= fixedB + 128UL * 262144UL)  Tc = 128;
  else if (ws_size >= fixedB + 64UL * 262144UL)   Tc = 64;
  size_t gBytes = (size_t)Tc * 262144UL;
  size_t oG = AL(gBytes);
  // overlay scores/M/hid onto G region (G dead once attention phase starts)
  size_t oSc, oM, oHid;
  if (gBytes >= 4194304UL + 2097152UL + 393216UL) {
    oSc = oG; oM = oG + 4194304UL; oHid = oG + 4194304UL + 2097152UL;
  } else {
    oSc = AL(4194304UL); oM = AL(2097152UL); oHid = AL(393216UL);
  }

  unsigned short* G    = (unsigned short*)(ws + oG);
  unsigned short* Hout = (unsigned short*)(ws + oHout);
  float* scores        = (float*)(ws + oSc);
  float* Mws           = (float*)(ws + oM);
  float* hid           = (float*)(ws + oHid);
  unsigned short* BihP = (unsigned short*)(ws + oBih);
  unsigned short* BhhP = (unsigned short*)(ws + oBhh);
  unsigned short* S1P  = (unsigned short*)(ws + oS1P);
  unsigned short* Hbuf = (unsigned short*)(ws + oHbuf);
  float* CSc           = (float*)(ws + oCSc);
  float* CSh           = (float*)(ws + oCSh);
  int* flags           = (int*)(ws + oFlag);

  hipLaunchKernelGGL(k_pack, dim3(4741), dim3(256), 0, stream,
                     Wih_f, Wih_b, Whh_f, Whh_b, S1, BihP, BhhP, S1P, flags, dout);

  int nchunk = 1024 / Tc;
  int gx = Tc / 32;
  for (int c = 0; c < nchunk; ++c) {
    hipLaunchKernelGGL(k_xgemm, dim3(gx, 64, 4), dim3(256), 0, stream,
                       ids, len, emb, BihP, G, c, Tc);
    hipLaunchKernelGGL(k_rnn, dim3(64), dim3(256), 0, stream,
                       G, BhhP, Hbuf, Hout, flags, len, h0, c0, CSc, CSh, dout,
                       c * Tc, Tc, Tc);
  }

  hipLaunchKernelGGL(k_scores, dim3(8, 64), dim3(256), 0, stream, Hout, S1P, S2, scores);
  hipLaunchKernelGGL(k_softmax, dim3(64, 16), dim3(256), 0, stream, scores, len, dout);
  hipLaunchKernelGGL(k_penal, dim3(64), dim3(256), 0, stream, dout);
  hipLaunchKernelGGL(k_attnM, dim3(64, 4), dim3(256), 0, stream, dout, Hout, len, Mws);
  hipLaunchKernelGGL(k_head1, dim3(32), dim3(256), 0, stream, W_et, b_et, Mws, hid);
  hipLaunchKernelGGL(k_head1, dim3(32), dim3(256), 0, stream, W_prt, b_prt, Mws, hid + 32768);
  hipLaunchKernelGGL(k_head1, dim3(32), dim3(256), 0, stream, W_popt, b_popt, Mws, hid + 65536);
  hipLaunchKernelGGL(k_head2, dim3(1), dim3(256), 0, stream, hid, Wd_et, bd_et, dout + DO_ET, 50);
  hipLaunchKernelGGL(k_head2, dim3(1), dim3(256), 0, stream, hid + 32768, Wd_prt, bd_prt, dout + DO_PRT, 12);
  hipLaunchKernelGGL(k_head2, dim3(1), dim3(256), 0, stream, hid + 65536, Wd_popt, bd_popt, dout + DO_POPT, 8);
}

// Round 5
// 3474.210 us; speedup vs baseline: 2.3250x; 1.2840x over previous
//
#include <hip/hip_runtime.h>
#include <cstdint>
#include <cstddef>

typedef short bf16x8 __attribute__((ext_vector_type(8)));
typedef float f32x4 __attribute__((ext_vector_type(4)));

#define DEVI static __device__ __forceinline__

DEVI unsigned short f2bf(float f) {
  union { float f; unsigned u; } v; v.f = f;
  unsigned r = (v.u + 0x7fffu + ((v.u >> 16) & 1u)) >> 16;
  return (unsigned short)r;
}
DEVI float bf2f(unsigned short s) {
  union { unsigned u; float f; } v; v.u = ((unsigned)s) << 16;
  return v.f;
}
DEVI float sigf(float x) { return 1.f / (1.f + __expf(-x)); }
DEVI float tanh_f(float x) {
  float xc = fminf(fmaxf(x, -15.f), 15.f);
  float e = __expf(2.f * xc);
  return 1.f - 2.f / (e + 1.f);
}
DEVI unsigned long long ldg_sc1_64(const unsigned long long* p) {
  return __hip_atomic_load(p, __ATOMIC_RELAXED, __HIP_MEMORY_SCOPE_AGENT);
}
DEVI void stg_sc1(unsigned* p, unsigned v) {
  __hip_atomic_store(p, v, __ATOMIC_RELAXED, __HIP_MEMORY_SCOPE_AGENT);
}

// d_out float offsets
#define DO_ET     0
#define DO_PRT    3200
#define DO_POPT   3968
#define DO_H      4480
#define DO_C      37248
#define DO_PENAL  70016
#define DO_A      70017

// ================= K1: pack weights (bf16, fragment-major), zero flags/penal ==============
__global__ __launch_bounds__(256) void k_pack(
    const float* __restrict__ Wih_f, const float* __restrict__ Wih_b,
    const float* __restrict__ Whh_f, const float* __restrict__ Whh_b,
    const float* __restrict__ S1,
    unsigned short* __restrict__ BihP, unsigned short* __restrict__ BhhP,
    unsigned short* __restrict__ S1P, int* __restrict__ flags, float* __restrict__ dout)
{
  int idx = blockIdx.x * 256 + threadIdx.x;
  if (idx < 655360) {
    // Bih: [d][kb=40][n=1024][j=8]; n = ht*128 + g*32 + u -> orig col g*256+ht*32+u
    int d = idx / 327680; int e = idx % 327680;
    int kb = e / 8192; int rem = e % 8192; int n = rem >> 3; int j = rem & 7;
    int k = kb * 8 + j;
    int col = ((n >> 5) & 3) * 256 + ((n >> 7) << 5) + (n & 31);
    const float* W = d ? Wih_b : Wih_f;
    float v = (k < 300) ? W[col * 300 + k] : 0.f;
    BihP[idx] = f2bf(v);
  } else if (idx < 1179648) {
    // Bhh: [d][ht=8][kb=32][c=128][j=8]; per-(d,ht) block = 32768 shorts
    int e = idx - 655360;
    int d = e >> 18; int e2 = e & 262143;
    int ht = (e2 >> 15) & 7; int kb = (e2 >> 10) & 31; int c = (e2 >> 3) & 127; int j = e2 & 7;
    int k = kb * 8 + j;
    int row = ((c >> 5) << 8) + (ht << 5) + (c & 31);
    const float* W = d ? Whh_b : Whh_f;
    BhhP[e] = f2bf(W[row * 256 + k]);
  } else if (idx < 1212416) {
    // S1P: [kb=64][da=64][j=8]
    int e = idx - 1179648;
    int j = e & 7; int da = (e >> 3) & 63; int kb = e >> 9;
    S1P[e] = f2bf(S1[da * 512 + kb * 8 + j]);
  } else if (idx < 1213440) {
    flags[idx - 1212416] = 0;
  } else if (idx == 1213440) {
    dout[DO_PENAL] = 0.f;
  }
}

// ================= K3: fully-fused persistent BiLSTM (x-GEMM in-kernel, no G buffer) =====
// 64 WGs: blk&7 = group g=(d,bt) [XCD-affinity], blk>>3 = ht (128 gate-cols).
// Wih slice (80KB) in LDS, Whh slice register-resident, X double-buffered in LDS,
// emb prefetched 1 step ahead. Fence-free sc1 handshake (round-4-proven).
__global__ __launch_bounds__(256, 1) void k_rnn(
    const int* __restrict__ ids, const float* __restrict__ emb,
    const unsigned short* __restrict__ BihP, const unsigned short* __restrict__ BhhP,
    unsigned short* __restrict__ Hbuf, unsigned short* __restrict__ Hout, int* flags,
    const int* __restrict__ len, const float* __restrict__ h0, const float* __restrict__ c0,
    float* __restrict__ dout)
{
  int blk = blockIdx.x;
  int ht = blk >> 3; int g = blk & 7; int d = g >> 2; int bt = g & 3;
  int tid = threadIdx.x;
  int lane = tid & 63, w = tid >> 6, l15 = lane & 15, quad = lane >> 4;
  int b0 = bt * 16;

  __shared__ unsigned short Wl[40960];    // Wih slice [kb=40][c=128][j=8]  (80 KB)
  __shared__ unsigned short Xl[2][5120];  // X dbuf [kb=40][m=16][j=8]      (20 KB)
  __shared__ unsigned short h0p[4096];    // h0 [kb=32][m=16][j=8]          (8 KB)
  __shared__ float gatesL[2048];          // [gate=4][b=16][u=32]           (8 KB)
  __shared__ int lenS[16];

  // ---- stage Wih slice into LDS (contiguous 1024-short runs per kb) ----
  {
    const unsigned* src = (const unsigned*)(BihP + (size_t)d * 327680);
    unsigned* dstW = (unsigned*)Wl;
    for (int kb = 0; kb < 40; ++kb) {
      int gb = ((kb * 1024 + ht * 128) * 8) >> 1;
      for (int i = tid; i < 512; i += 256)
        dstW[kb * 512 + i] = src[gb + i];
    }
  }
  // ---- h0 -> LDS (A-fragment layout) ----
  for (int i = tid; i < 4096; i += 256) {
    int kb = i >> 7, mm = (i >> 3) & 15, j = i & 7;
    h0p[i] = f2bf(h0[d * 16384 + (b0 + mm) * 256 + kb * 8 + j]);
  }
  if (tid < 16) lenS[tid] = len[b0 + tid];
  // ---- zero X pad rows kb=38,39 (k=304..319), both buffers ----
  for (int i = tid; i < 128; i += 256) {
    ((unsigned*)Xl[0])[2432 + i] = 0;
    ((unsigned*)Xl[1])[2432 + i] = 0;
  }
  // ---- Whh slice -> registers (per-(d,ht) block = 32768 shorts) ----
  const unsigned short* Bw = BhhP + (size_t)(d * 8 + ht) * 32768;
  bf16x8 bfr[8][2];
  #pragma unroll
  for (int kc = 0; kc < 8; ++kc)
    #pragma unroll
    for (int nt = 0; nt < 2; ++nt)
      bfr[kc][nt] = *reinterpret_cast<const bf16x8*>(
          Bw + ((size_t)(kc * 4 + quad) * 128 + w * 32 + nt * 16 + l15) * 8);

  __syncthreads();  // lenS/Wl/h0p/X-pad ready

  // ---- stage X_0 into Xl[0] ----
  int xm = tid >> 4, xf = tid & 15;
  {
    int lbm = lenS[xm];
    int s = d ? (lbm - 1) : 0;
    s = s < 0 ? 0 : (s > 1023 ? 1023 : s);
    int tok = ids[(b0 + xm) * 1024 + s];
    const float* er = emb + (size_t)tok * 300;
    #pragma unroll
    for (int i = 0; i < 5; ++i) {
      int f = xf + 16 * i;
      float4 v = (f <= 74) ? *reinterpret_cast<const float4*>(er + 4 * f)
                           : (float4){0.f, 0.f, 0.f, 0.f};
      if (f < 76) {
        int uo = ((f >> 1) * 16 + xm) * 4 + (f & 1) * 2;
        ((unsigned*)Xl[0])[uo]     = (unsigned)f2bf(v.x) | ((unsigned)f2bf(v.y) << 16);
        ((unsigned*)Xl[0])[uo + 1] = (unsigned)f2bf(v.z) | ((unsigned)f2bf(v.w) << 16);
      }
    }
  }
  __syncthreads();

  int b_l = tid >> 4, u2 = tid & 15;
  int len_b = lenS[b_l];
  int Tmax = lenS[0];  // lens sorted descending -> row 0 is tile max
  int cidx = d * 16384 + (b0 + b_l) * 256 + ht * 32 + 2 * u2;
  float cc0 = c0[cidx], cc1 = c0[cidx + 1];
  float hh0 = h0[cidx], hh1 = h0[cidx + 1];

  unsigned short* HbufG = Hbuf + (size_t)g * 8192;  // 2 slots x 4096 shorts
  int* fl = flags + g * 128;

  for (int t = 0; t < Tmax; ++t) {
    // ---- prefetch X_{t+1} raw (HBM latency hidden behind this step) ----
    float4 xr[5];
    {
      int tn = t + 1;
      int s = d ? (lenS[xm] - 1 - tn) : tn;
      s = s < 0 ? 0 : (s > 1023 ? 1023 : s);
      int tok = ids[(b0 + xm) * 1024 + s];
      const float* er = emb + (size_t)tok * 300;
      #pragma unroll
      for (int i = 0; i < 5; ++i) {
        int f = xf + 16 * i;
        xr[i] = (f <= 74) ? *reinterpret_cast<const float4*>(er + 4 * f)
                          : (float4){0.f, 0.f, 0.f, 0.f};
      }
    }

    // ---- x-part MFMA (independent of h -> before the spin) ----
    f32x4 ac0 = {0.f, 0.f, 0.f, 0.f}, ac1 = {0.f, 0.f, 0.f, 0.f};
    {
      const unsigned short* Xb = Xl[t & 1];
      #pragma unroll
      for (int kc = 0; kc < 10; ++kc) {
        int kb = kc * 4 + quad;
        bf16x8 ax  = *reinterpret_cast<const bf16x8*>(&Xb[(kb * 16 + l15) * 8]);
        bf16x8 bx0 = *reinterpret_cast<const bf16x8*>(&Wl[kb * 1024 + (w * 32 + l15) * 8]);
        bf16x8 bx1 = *reinterpret_cast<const bf16x8*>(&Wl[kb * 1024 + (w * 32 + 16 + l15) * 8]);
        ac0 = __builtin_amdgcn_mfma_f32_16x16x32_bf16(ax, bx0, ac0, 0, 0, 0);
        ac1 = __builtin_amdgcn_mfma_f32_16x16x32_bf16(ax, bx1, ac1, 0, 0, 0);
      }
    }

    // ---- spin for h_{t-1}, then h-part MFMA ----
    bf16x8 ah[8];
    if (t == 0) {
      #pragma unroll
      for (int kc = 0; kc < 8; ++kc)
        ah[kc] = *reinterpret_cast<const bf16x8*>(&h0p[((kc * 4 + quad) * 16 + l15) * 8]);
    } else {
      int polls = 0;
      while (true) {
        int v = 0x7fffffff;
        if (lane < 8)
          v = __hip_atomic_load(fl + lane * 16, __ATOMIC_RELAXED, __HIP_MEMORY_SCOPE_AGENT);
        if (__ballot(v >= t) == ~0ull) break;
        if (++polls > 100000) break;  // failsafe (never fires when protocol healthy)
      }
      asm volatile("" ::: "memory");
      const unsigned long long* slotU =
          (const unsigned long long*)(HbufG + (size_t)(t & 1) * 4096);
      #pragma unroll
      for (int kc = 0; kc < 8; ++kc) {
        int qo = (((kc * 4 + quad) * 16 + l15) * 4) >> 1;  // u64 index
        union { unsigned long long q[2]; bf16x8 v; } tu;
        tu.q[0] = ldg_sc1_64(slotU + qo);
        tu.q[1] = ldg_sc1_64(slotU + qo + 1);
        ah[kc] = tu.v;
      }
    }
    #pragma unroll
    for (int kc = 0; kc < 8; ++kc) {
      ac0 = __builtin_amdgcn_mfma_f32_16x16x32_bf16(ah[kc], bfr[kc][0], ac0, 0, 0, 0);
      ac1 = __builtin_amdgcn_mfma_f32_16x16x32_bf16(ah[kc], bfr[kc][1], ac1, 0, 0, 0);
    }

    #pragma unroll
    for (int r = 0; r < 4; ++r) {
      gatesL[(w * 16 + quad * 4 + r) * 32 + l15] = ac0[r];
      gatesL[(w * 16 + quad * 4 + r) * 32 + 16 + l15] = ac1[r];
    }
    __syncthreads();  // B1

    float gi0 = gatesL[(0 * 16 + b_l) * 32 + 2 * u2], gi1 = gatesL[(0 * 16 + b_l) * 32 + 2 * u2 + 1];
    float gf0 = gatesL[(1 * 16 + b_l) * 32 + 2 * u2], gf1 = gatesL[(1 * 16 + b_l) * 32 + 2 * u2 + 1];
    float gg0 = gatesL[(2 * 16 + b_l) * 32 + 2 * u2], gg1 = gatesL[(2 * 16 + b_l) * 32 + 2 * u2 + 1];
    float go0 = gatesL[(3 * 16 + b_l) * 32 + 2 * u2], go1 = gatesL[(3 * 16 + b_l) * 32 + 2 * u2 + 1];

    if (t < len_b) {
      float cn0 = sigf(gf0) * cc0 + sigf(gi0) * tanh_f(gg0);
      float cn1 = sigf(gf1) * cc1 + sigf(gi1) * tanh_f(gg1);
      cc0 = cn0; cc1 = cn1;
      hh0 = sigf(go0) * tanh_f(cn0);
      hh1 = sigf(go1) * tanh_f(cn1);
    }

    int k = ht * 32 + 2 * u2;
    unsigned hp = (unsigned)f2bf(hh0) | ((unsigned)f2bf(hh1) << 16);
    unsigned soff = ((unsigned)(k >> 3) * 128 + b_l * 8 + (k & 7)) >> 1;
    stg_sc1((unsigned*)(HbufG + (size_t)((t + 1) & 1) * 4096) + soff, hp);

    // ---- convert prefetched X_{t+1} into the other LDS buffer ----
    {
      unsigned* LX = (unsigned*)Xl[(t + 1) & 1];
      #pragma unroll
      for (int i = 0; i < 5; ++i) {
        int f = xf + 16 * i;
        if (f < 76) {
          int uo = ((f >> 1) * 16 + xm) * 4 + (f & 1) * 2;
          LX[uo]     = (unsigned)f2bf(xr[i].x) | ((unsigned)f2bf(xr[i].y) << 16);
          LX[uo + 1] = (unsigned)f2bf(xr[i].z) | ((unsigned)f2bf(xr[i].w) << 16);
        }
      }
    }

    __syncthreads();  // B2: drains vmcnt -> sc1 h-stores complete; Xl visible
    if (tid == 0)
      __hip_atomic_store(fl + ht * 16, t + 1, __ATOMIC_RELAXED, __HIP_MEMORY_SCOPE_AGENT);

    // ---- epilogue off the inter-WG critical path ----
    size_t hob = (size_t)(b0 + b_l) * 524288;
    if (d == 0) {
      *reinterpret_cast<unsigned*>(Hout + hob + (size_t)t * 512 + k) = hp;
    } else if (t < len_b) {
      *reinterpret_cast<unsigned*>(Hout + hob + (size_t)(len_b - 1 - t) * 512 + 256 + k) = hp;
    }
    if (t == len_b - 1) {
      dout[DO_H + cidx] = hh0; dout[DO_H + cidx + 1] = hh1;
      dout[DO_C + cidx] = cc0; dout[DO_C + cidx + 1] = cc1;
    }
  }
}

// ================= K4: scores = tanh(Hout @ S1^T) @ S2^T ==========
__global__ __launch_bounds__(256, 2) void k_scores(
    const unsigned short* __restrict__ Hout, const unsigned short* __restrict__ S1P,
    const float* __restrict__ S2, float* __restrict__ scores)
{
  __shared__ float U[128 * 65];
  __shared__ float S2l[16 * 65];
  int tid = threadIdx.x;
  int t0 = blockIdx.x * 128;
  int b = blockIdx.y;
  int lane = tid & 63, w = tid >> 6, l15 = lane & 15, quad = lane >> 4;

  f32x4 acc[2][4];
  #pragma unroll
  for (int i = 0; i < 2; ++i)
    #pragma unroll
    for (int j = 0; j < 4; ++j) acc[i][j] = (f32x4){0.f, 0.f, 0.f, 0.f};

  for (int kc = 0; kc < 16; ++kc) {
    bf16x8 afr[2];
    #pragma unroll
    for (int mt = 0; mt < 2; ++mt) {
      int row = t0 + w * 32 + mt * 16 + l15;
      afr[mt] = *reinterpret_cast<const bf16x8*>(
          Hout + (size_t)b * 524288 + (size_t)row * 512 + kc * 32 + quad * 8);
    }
    bf16x8 bfr[4];
    #pragma unroll
    for (int nt = 0; nt < 4; ++nt)
      bfr[nt] = *reinterpret_cast<const bf16x8*>(
          S1P + ((size_t)(kc * 4 + quad) * 64 + nt * 16 + l15) * 8);
    #pragma unroll
    for (int mt = 0; mt < 2; ++mt)
      #pragma unroll
      for (int nt = 0; nt < 4; ++nt)
        acc[mt][nt] = __builtin_amdgcn_mfma_f32_16x16x32_bf16(afr[mt], bfr[nt], acc[mt][nt], 0, 0, 0);
  }
  #pragma unroll
  for (int mt = 0; mt < 2; ++mt)
    #pragma unroll
    for (int nt = 0; nt < 4; ++nt)
      #pragma unroll
      for (int r = 0; r < 4; ++r)
        U[(w * 32 + mt * 16 + quad * 4 + r) * 65 + nt * 16 + l15] = acc[mt][nt][r];
  for (int i = tid; i < 1024; i += 256) S2l[(i >> 6) * 65 + (i & 63)] = S2[i];
  __syncthreads();
  for (int i = tid; i < 8192; i += 256) {
    int row = i >> 6, c = i & 63;
    U[row * 65 + c] = tanh_f(U[row * 65 + c]);
  }
  __syncthreads();
  for (int idx = tid; idx < 2048; idx += 256) {
    int row = idx >> 4, r = idx & 15;
    float s = 0.f;
    #pragma unroll 8
    for (int da = 0; da < 64; ++da) s += U[row * 65 + da] * S2l[r * 65 + da];
    scores[((size_t)b * 16 + r) * 1024 + t0 + row] = s;
  }
}

// ================= K5: masked softmax -> A (exact zeros past len) =========
__global__ __launch_bounds__(256) void k_softmax(
    const float* __restrict__ scores, const int* __restrict__ len, float* __restrict__ dout)
{
  __shared__ float red[256];
  int b = blockIdx.x, r = blockIdx.y;
  int tid = threadIdx.x;
  int lb = len[b];
  const float* src = scores + ((size_t)b * 16 + r) * 1024;
  float v[4]; float mx = -3.0e38f;
  #pragma unroll
  for (int i = 0; i < 4; ++i) {
    int t = tid + i * 256;
    v[i] = (t < lb) ? src[t] : -3.0e38f;
    mx = fmaxf(mx, v[i]);
  }
  red[tid] = mx; __syncthreads();
  for (int s = 128; s > 0; s >>= 1) { if (tid < s) red[tid] = fmaxf(red[tid], red[tid + s]); __syncthreads(); }
  float M = red[0]; __syncthreads();
  float se = 0.f;
  #pragma unroll
  for (int i = 0; i < 4; ++i) {
    int t = tid + i * 256;
    if (t < lb) { v[i] = __expf(v[i] - M); se += v[i]; }
  }
  red[tid] = se; __syncthreads();
  for (int s = 128; s > 0; s >>= 1) { if (tid < s) red[tid] += red[tid + s]; __syncthreads(); }
  float inv = 1.f / red[0];
  float* dst = dout + DO_A + ((size_t)b * 16 + r) * 1024;
  #pragma unroll
  for (int i = 0; i < 4; ++i) {
    int t = tid + i * 256;
    dst[t] = (t < lb) ? v[i] * inv : 0.f;
  }
}

// ================= K6: penal (2-pass, <=34KB LDS) =================
__global__ __launch_bounds__(256) void k_penal(float* __restrict__ dout)
{
  __shared__ float Al[16 * 513];
  __shared__ float red[256];
  int b = blockIdx.x, tid = threadIdx.x;
  const float* A = dout + DO_A + (size_t)b * 16384;
  int r = tid >> 4, q = tid & 15;
  float s = 0.f;
  for (int half = 0; half < 2; ++half) {
    __syncthreads();
    for (int i = tid; i < 8192; i += 256) {
      int rr = i >> 9, t = i & 511;
      Al[rr * 513 + t] = A[rr * 1024 + half * 512 + t];
    }
    __syncthreads();
    for (int t = 0; t < 512; ++t) s += Al[r * 513 + t] * Al[q * 513 + t];
  }
  float dv = s - ((r == q) ? 1.f : 0.f);
  red[tid] = dv * dv; __syncthreads();
  for (int st = 128; st > 0; st >>= 1) { if (tid < st) red[tid] += red[tid + st]; __syncthreads(); }
  if (tid == 0) atomicAdd(dout + DO_PENAL, red[0] * (1.f / 64.f));
}

// ================= K7: M = A @ Hout -> BM [64][8192] =================
__global__ __launch_bounds__(256) void k_attnM(
    const float* __restrict__ dout, const unsigned short* __restrict__ Hout,
    const int* __restrict__ len, float* __restrict__ Mws)
{
  int b = blockIdx.x, dc = blockIdx.y;
  int tid = threadIdx.x;
  int col = dc * 128 + (tid & 127);
  int rh = tid >> 7;
  int lb = len[b];
  const float* Ab = dout + DO_A + (size_t)b * 16384;
  const unsigned short* Hb = Hout + (size_t)b * 524288;
  float acc[8];
  #pragma unroll
  for (int i = 0; i < 8; ++i) acc[i] = 0.f;
  for (int t = 0; t < lb; ++t) {
    float h = bf2f(Hb[(size_t)t * 512 + col]);
    #pragma unroll
    for (int rr = 0; rr < 8; ++rr) acc[rr] += Ab[(rh * 8 + rr) * 1024 + t] * h;
  }
  #pragma unroll
  for (int rr = 0; rr < 8; ++rr) Mws[(size_t)b * 8192 + (rh * 8 + rr) * 512 + col] = acc[rr];
}

// ================= K8a: K-split partial GEMM: P[ks][b][n] = BM[b][ksK] @ W[n][ksK]^T ======
__global__ __launch_bounds__(256) void k_heads1(
    const float* __restrict__ W, const float* __restrict__ Mws, float* __restrict__ P)
{
  int tid = threadIdx.x;
  int n = blockIdx.x * 16 + (tid & 15);
  int ks = blockIdx.y;
  int bg = tid >> 4;
  const float* Wr = W + (size_t)n * 8192 + ks * 1024;
  float acc[4] = {0.f, 0.f, 0.f, 0.f};
  for (int k = 0; k < 1024; k += 4) {
    float4 wv = *reinterpret_cast<const float4*>(Wr + k);
    #pragma unroll
    for (int i = 0; i < 4; ++i) {
      float4 mv = *reinterpret_cast<const float4*>(Mws + (size_t)(bg * 4 + i) * 8192 + ks * 1024 + k);
      acc[i] += wv.x * mv.x + wv.y * mv.y + wv.z * mv.z + wv.w * mv.w;
    }
  }
  #pragma unroll
  for (int i = 0; i < 4; ++i)
    P[(size_t)(ks * 64 + bg * 4 + i) * 512 + n] = acc[i];
}

// ================= K8b: reduce partials + bias + relu -> hid[3][64][512] =================
__global__ __launch_bounds__(256) void k_headred(
    const float* __restrict__ Pws, const float* __restrict__ b_et,
    const float* __restrict__ b_prt, const float* __restrict__ b_popt,
    float* __restrict__ hid)
{
  int idx = blockIdx.x * 256 + threadIdx.x;  // 3*64*512 = 98304
  int head = idx >> 15; int rem = idx & 32767;
  int b = rem >> 9; int n = rem & 511;
  const float* bias = (head == 0) ? b_et : (head == 1) ? b_prt : b_popt;
  float s = bias[n];
  #pragma unroll
  for (int ks = 0; ks < 8; ++ks)
    s += Pws[(size_t)(head * 8 + ks) * 32768 + b * 512 + n];
  hid[idx] = fmaxf(s, 0.f);
}

// ================= K8c: decoded = hidden @ Wd^T + bd =================
__global__ __launch_bounds__(256) void k_head2(
    const float* __restrict__ hid, const float* __restrict__ Wd, const float* __restrict__ bd,
    float* __restrict__ out, int No)
{
  int idx = blockIdx.x * 256 + threadIdx.x;
  if (idx >= 64 * No) return;
  int b = idx / No, o = idx % No;
  const float* hv = hid + (size_t)b * 512;
  const float* wr = Wd + (size_t)o * 512;
  float acc = bd[o];
  for (int k = 0; k < 512; k += 4) {
    float4 h4 = *reinterpret_cast<const float4*>(hv + k);
    float4 w4 = *reinterpret_cast<const float4*>(wr + k);
    acc += h4.x * w4.x + h4.y * w4.y + h4.z * w4.z + h4.w * w4.w;
  }
  out[idx] = acc;
}

extern "C" void kernel_launch(void* const* d_in, const int* in_sizes, int n_in,
                              void* d_out, int out_size, void* d_ws, size_t ws_size,
                              hipStream_t stream) {
  const int*   ids    = (const int*)d_in[0];
  const int*   len    = (const int*)d_in[1];
  const float* h0     = (const float*)d_in[2];
  const float* c0     = (const float*)d_in[3];
  const float* emb    = (const float*)d_in[4];
  const float* Wih_f  = (const float*)d_in[5];
  const float* Whh_f  = (const float*)d_in[6];
  const float* Wih_b  = (const float*)d_in[7];
  const float* Whh_b  = (const float*)d_in[8];
  const float* S1     = (const float*)d_in[9];
  const float* S2     = (const float*)d_in[10];
  const float* W_et   = (const float*)d_in[11];
  const float* b_et   = (const float*)d_in[12];
  const float* Wd_et  = (const float*)d_in[13];
  const float* bd_et  = (const float*)d_in[14];
  const float* W_prt  = (const float*)d_in[15];
  const float* b_prt  = (const float*)d_in[16];
  const float* Wd_prt = (const float*)d_in[17];
  const float* bd_prt = (const float*)d_in[18];
  const float* W_popt = (const float*)d_in[19];
  const float* b_popt = (const float*)d_in[20];
  const float* Wd_popt= (const float*)d_in[21];
  const float* bd_popt= (const float*)d_in[22];
  float* dout = (float*)d_out;
  char* ws = (char*)d_ws;

  // ---- workspace layout (fixed, ~73.5 MiB; proven ws floor >= ~81 MB) ----
  size_t off = 0;
  auto AL = [&](size_t bytes) { size_t r = off; off += (bytes + 255) & ~(size_t)255; return r; };
  size_t oHout = AL(67108864UL);   // [64][1024][512] bf16
  size_t oBih  = AL(1310720UL);    // packed W_ih
  size_t oBhh  = AL(1048576UL);    // packed W_hh
  size_t oS1P  = AL(65536UL);      // packed S1
  size_t oHbuf = AL(131072UL);     // 8 groups x 2 slots x 4096 bf16
  size_t oFlag = AL(4096UL);
  size_t oPws  = AL(3145728UL);    // [3][8][64][512] f32 head partials
  size_t oSc   = AL(4194304UL);    // scores [64][16][1024] f32
  size_t oM    = oSc;              // overlay: M (2 MB) after scores dead
  size_t oHid  = oSc + 2097152UL;  // overlay: hid (384 KB)

  unsigned short* Hout = (unsigned short*)(ws + oHout);
  unsigned short* BihP = (unsigned short*)(ws + oBih);
  unsigned short* BhhP = (unsigned short*)(ws + oBhh);
  unsigned short* S1P  = (unsigned short*)(ws + oS1P);
  unsigned short* Hbuf = (unsigned short*)(ws + oHbuf);
  int* flags           = (int*)(ws + oFlag);
  float* Pws           = (float*)(ws + oPws);
  float* scores        = (float*)(ws + oSc);
  float* Mws           = (float*)(ws + oM);
  float* hid           = (float*)(ws + oHid);

  hipLaunchKernelGGL(k_pack, dim3(4741), dim3(256), 0, stream,
                     Wih_f, Wih_b, Whh_f, Whh_b, S1, BihP, BhhP, S1P, flags, dout);
  hipLaunchKernelGGL(k_rnn, dim3(64), dim3(256), 0, stream,
                     ids, emb, BihP, BhhP, Hbuf, Hout, flags, len, h0, c0, dout);
  hipLaunchKernelGGL(k_scores, dim3(8, 64), dim3(256), 0, stream, Hout, S1P, S2, scores);
  hipLaunchKernelGGL(k_softmax, dim3(64, 16), dim3(256), 0, stream, scores, len, dout);
  hipLaunchKernelGGL(k_penal, dim3(64), dim3(256), 0, stream, dout);
  hipLaunchKernelGGL(k_attnM, dim3(64, 4), dim3(256), 0, stream, dout, Hout, len, Mws);
  hipLaunchKernelGGL(k_heads1, dim3(32, 8), dim3(256), 0, stream, W_et,   Mws, Pws);
  hipLaunchKernelGGL(k_heads1, dim3(32, 8), dim3(256), 0, stream, W_prt,  Mws, Pws + 262144);
  hipLaunchKernelGGL(k_heads1, dim3(32, 8), dim3(256), 0, stream, W_popt, Mws, Pws + 524288);
  hipLaunchKernelGGL(k_headred, dim3(384), dim3(256), 0, stream, Pws, b_et, b_prt, b_popt, hid);
  hipLaunchKernelGGL(k_head2, dim3(13), dim3(256), 0, stream, hid,         Wd_et,   bd_et,   dout + DO_ET, 50);
  hipLaunchKernelGGL(k_head2, dim3(3),  dim3(256), 0, stream, hid + 32768, Wd_prt,  bd_prt,  dout + DO_PRT, 12);
  hipLaunchKernelGGL(k_head2, dim3(2),  dim3(256), 0, stream, hid + 65536, Wd_popt, bd_popt, dout + DO_POPT, 8);
}